// Round 1
// baseline (10845.200 us; speedup 1.0000x reference)
//
#include <hip/hip_runtime.h>
#include <hip/hip_cooperative_groups.h>
#include <cmath>

namespace cg = cooperative_groups;

using v8bf  = __attribute__((ext_vector_type(8))) __bf16;
using f32x4 = __attribute__((ext_vector_type(4))) float;

#define TSTEPS  200
#define BATCH   256
#define IN_SZ   4
#define HID     1000
#define HP      1024   // padded hidden
#define NWG     64     // hidden cols per WG
#define MWG     16     // batch rows per WG
#define NBLK    16     // HP/NWG
#define MBLK    16     // BATCH/MWG

__device__ __forceinline__ void gsync(cg::grid_group& g) {
  __builtin_amdgcn_fence(__ATOMIC_RELEASE, "agent");
  g.sync();
  __builtin_amdgcn_fence(__ATOMIC_ACQUIRE, "agent");
}

// Persistent cooperative kernel: whole recurrence, one grid.sync per step.
// Grid 256 x 256 threads. bid&15 = mb (batch block), bid>>4 = nb (hidden block).
// Same-mb WGs land on the same XCDs (bid%8 pattern) -> A rows served from local L2.
__global__ __launch_bounds__(256, 1) void elman_rnn(
    const float* __restrict__ input,   // [T][B][4]
    const float* __restrict__ W_in,    // [HID][4]
    const float* __restrict__ b_in,    // [HID]
    const float* __restrict__ W_hh,    // [HID][HID]
    const float* __restrict__ b_hh,    // [HID]
    const float* __restrict__ W_fc,    // [2][HID]
    __bf16* __restrict__ h_buf,        // [2][B][HP] bf16, double buffer
    float* __restrict__ partial)       // [T][NBLK][B][2] fp32 fc partials
{
  const int tid  = threadIdx.x;
  const int bid  = blockIdx.x;
  const int mb   = bid & 15;
  const int nb   = bid >> 4;
  const int lane = tid & 63;
  const int w    = tid >> 6;      // wave 0..3
  const int l15  = lane & 15;
  const int g4   = lane >> 4;     // 0..3

  __shared__ float4 win_s[NWG];
  __shared__ float  bias_s[NWG];
  __shared__ float  wfc_s[NWG][2];
  __shared__ __bf16 out_s[MWG][72];   // 72 stride: pad to dodge bank conflicts
  __shared__ float  fc_s[4][MWG][2];

  // ---- per-WG constants ----
  if (tid < NWG) {
    int n = nb * NWG + tid;
    bool ok = (n < HID);
    bias_s[tid] = ok ? (b_in[n] + b_hh[n]) : 0.f;
    win_s[tid]  = ok ? *reinterpret_cast<const float4*>(W_in + n * 4)
                     : make_float4(0.f, 0.f, 0.f, 0.f);
    wfc_s[tid][0] = ok ? W_fc[n] : 0.f;
    wfc_s[tid][1] = ok ? W_fc[HID + n] : 0.f;
  }

  // ---- load this wave's W_hh slice as MFMA B-fragments, held in VGPRs for the
  //      entire kernel (16 n-rows x 1024 k = 32KB/wave = 128 VGPR) ----
  const int n_loc  = (w << 4) + l15;       // [0,64) within WG
  const int n_glob = nb * NWG + n_loc;     // global hidden index (column of h_new)
  v8bf bfrag[32];
  #pragma unroll
  for (int s = 0; s < 32; ++s) {
    const int k0 = s * 32 + (g4 << 3);
    v8bf v;
    if (n_glob < HID && k0 < HID) {        // k0<HID => k0+7<=999 (1000%8==0)
      const float4* p = reinterpret_cast<const float4*>(W_hh + (size_t)n_glob * HID + k0);
      float4 f0 = p[0], f1 = p[1];
      v[0] = (__bf16)f0.x; v[1] = (__bf16)f0.y; v[2] = (__bf16)f0.z; v[3] = (__bf16)f0.w;
      v[4] = (__bf16)f1.x; v[5] = (__bf16)f1.y; v[6] = (__bf16)f1.z; v[7] = (__bf16)f1.w;
    } else {
      #pragma unroll
      for (int j = 0; j < 8; ++j) v[j] = (__bf16)0.f;
    }
    bfrag[s] = v;
  }

  // ---- zero h0 (this WG's 16x64 slice of buffer 0) ----
  {
    int r = tid >> 4;            // 0..15
    int c = (tid & 15) << 2;     // 0..60 step 4 (4 bf16 = 8B)
    unsigned long long* p = reinterpret_cast<unsigned long long*>(
        h_buf + (size_t)(mb * MWG + r) * HP + nb * NWG + c);
    *p = 0ull;
  }

  cg::grid_group grid = cg::this_grid();
  gsync(grid);

  const int arow = mb * MWG + l15;         // this lane's A row (batch index)

  for (int t = 0; t < TSTEPS; ++t) {
    const __bf16* hcur = h_buf + (size_t)(t & 1) * BATCH * HP;
    __bf16*       hnxt = h_buf + (size_t)((t & 1) ^ 1) * BATCH * HP;
    const __bf16* abase = hcur + (size_t)arow * HP + (g4 << 3);

    // A fragments: 32 x dwordx4 with immediate offsets (s*64B), all in flight
    v8bf a[32];
    #pragma unroll
    for (int s = 0; s < 32; ++s)
      a[s] = *reinterpret_cast<const v8bf*>(abase + s * 32);

    // 4 round-robin accumulators to break the dependent-MFMA chain
    f32x4 acc4[4];
    #pragma unroll
    for (int c = 0; c < 4; ++c) acc4[c] = f32x4{0.f, 0.f, 0.f, 0.f};

    #pragma unroll
    for (int s = 0; s < 32; ++s)
      acc4[s & 3] = __builtin_amdgcn_mfma_f32_16x16x32_bf16(a[s], bfrag[s], acc4[s & 3], 0, 0, 0);

    f32x4 acc;
    #pragma unroll
    for (int j = 0; j < 4; ++j)
      acc[j] = (acc4[0][j] + acc4[1][j]) + (acc4[2][j] + acc4[3][j]);

    // ---- epilogue: xp + bias, tanh, stage h_new, fc partials ----
    const float  bias = bias_s[n_loc];
    const float4 wi   = win_s[n_loc];
    const float  wf0  = wfc_s[n_loc][0];
    const float  wf1  = wfc_s[n_loc][1];

    float p0[4], p1[4];
    #pragma unroll
    for (int j = 0; j < 4; ++j) {
      const int m_loc  = (g4 << 2) + j;       // C row within tile
      const int b_glob = mb * MWG + m_loc;
      const float4 x = *reinterpret_cast<const float4*>(
          input + ((size_t)t * BATCH + b_glob) * IN_SZ);
      float pre = acc[j] + bias + x.x * wi.x + x.y * wi.y + x.z * wi.z + x.w * wi.w;
      float h = tanhf(pre);
      out_s[m_loc][n_loc] = (__bf16)h;
      p0[j] = h * wf0;
      p1[j] = h * wf1;
    }

    // reduce fc partials over the 16 lanes (= 16 hidden cols) of each group
    #pragma unroll
    for (int j = 0; j < 4; ++j) {
      float a0 = p0[j], a1 = p1[j];
      #pragma unroll
      for (int off = 8; off >= 1; off >>= 1) {
        a0 += __shfl_xor(a0, off, 64);
        a1 += __shfl_xor(a1, off, 64);
      }
      if (l15 == 0) {
        fc_s[w][(g4 << 2) + j][0] = a0;
        fc_s[w][(g4 << 2) + j][1] = a1;
      }
    }

    __syncthreads();

    if (tid < 32) {   // combine 4 waves' fc partials, write global partial
      int m = tid >> 1, o = tid & 1;
      float s = (fc_s[0][m][o] + fc_s[1][m][o]) + (fc_s[2][m][o] + fc_s[3][m][o]);
      partial[(((size_t)t * NBLK + nb) * BATCH + (mb * MWG + m)) * 2 + o] = s;
    }
    if (tid < 128) {  // coalesced 16B stores of h_new tile to global
      int r = tid >> 3, c = (tid & 7) << 3;
      v8bf v = *reinterpret_cast<const v8bf*>(&out_s[r][c]);
      *reinterpret_cast<v8bf*>(hnxt + (size_t)(mb * MWG + r) * HP + nb * NWG + c) = v;
    }

    gsync(grid);
  }
}

__global__ void fc_finish(const float* __restrict__ partial,
                          const float* __restrict__ b_fc,
                          float* __restrict__ out)
{
  const int t = blockIdx.x;       // 200 blocks
  const int tid = threadIdx.x;    // 512 = 256 b x 2 o
  const int o = tid & 1;
  float s = b_fc[o];
  #pragma unroll
  for (int p = 0; p < NBLK; ++p)
    s += partial[((size_t)t * NBLK + p) * (BATCH * 2) + tid];
  out[(size_t)t * 512 + tid] = tanhf(s);
}

extern "C" void kernel_launch(void* const* d_in, const int* in_sizes, int n_in,
                              void* d_out, int out_size, void* d_ws, size_t ws_size,
                              hipStream_t stream) {
  const float* input = (const float*)d_in[0];
  // d_in[1] = target (unused by the forward output)
  const float* W_in  = (const float*)d_in[2];
  const float* b_in  = (const float*)d_in[3];
  const float* W_hh  = (const float*)d_in[4];
  const float* b_hh  = (const float*)d_in[5];
  const float* W_fc  = (const float*)d_in[6];
  const float* b_fc  = (const float*)d_in[7];
  float* out = (float*)d_out;

  // workspace layout: [0, 1MiB) h double buffer (bf16), then fc partials (fp32)
  __bf16* h_buf   = (__bf16*)d_ws;
  float*  partial = (float*)((char*)d_ws + (size_t)2 * BATCH * HP * sizeof(__bf16));

  void* args[] = { (void*)&input, (void*)&W_in, (void*)&b_in, (void*)&W_hh,
                   (void*)&b_hh, (void*)&W_fc, (void*)&h_buf, (void*)&partial };
  hipLaunchCooperativeKernel((const void*)elman_rnn, dim3(256), dim3(256),
                             args, 0, stream);

  fc_finish<<<TSTEPS, 512, 0, stream>>>(partial, b_fc, out);
}

// Round 4
// 2498.600 us; speedup vs baseline: 4.3405x; 4.3405x over previous
//
#include <hip/hip_runtime.h>
#include <cmath>

using v8bf  = __attribute__((ext_vector_type(8))) __bf16;
using f32x4 = __attribute__((ext_vector_type(4))) float;

#define TSTEPS  200
#define BATCH   256
#define IN_SZ   4
#define HID     1000
#define HP      1024   // padded hidden
#define NWG     64     // hidden cols per WG
#define MWG     16     // batch rows per WG
#define NBLK    16     // hidden blocks  (= group size for the phase barrier)
#define MBLK    16     // batch blocks   (= number of groups)

// dynamic LDS layout (bytes)
#define W_LDS_BYTES   (NWG * HP * 2)                 // 131072: W_hh slice, fragment-major
#define OFF_WIN       (W_LDS_BYTES)                  // float4[64]   1024 B
#define OFF_BIAS      (OFF_WIN + 1024)               // float[64]     256 B
#define OFF_WFC       (OFF_BIAS + 256)               // float[64][2]  512 B
#define OFF_OUT       (OFF_WFC + 512)                // bf16[16][72] 2304 B
#define OFF_FCS       (OFF_OUT + 2304)               // float[4][16][2] 512 B
#define SMEM_BYTES    (OFF_FCS + 512)                // 135680 total

// workspace layout (bytes)
#define H_BYTES       ((size_t)2 * BATCH * HP * 2)   // 1 MiB: h double buffer (bf16)
#define CNT_BYTES     (MBLK * 256)                   // 16 counters, 256B apart
#define PARTIAL_OFF   (H_BYTES + CNT_BYTES)

// Persistent kernel: 256 WGs x 256 thr, 1 WG/CU. mb = bid&15 (batch block),
// nb = bid>>4 (hidden block). Only the 16 WGs sharing mb ever exchange data;
// they synchronize through a private phase barrier (counter in d_ws).
__global__ __launch_bounds__(256, 1) void elman_rnn(
    const float* __restrict__ input,   // [T][B][4]
    const float* __restrict__ W_in,    // [HID][4]
    const float* __restrict__ b_in,    // [HID]
    const float* __restrict__ W_hh,    // [HID][HID]
    const float* __restrict__ b_hh,    // [HID]
    const float* __restrict__ W_fc,    // [2][HID]
    __bf16* __restrict__ h_buf,        // [2][B][HP] bf16 (memset-0 on stream)
    unsigned* __restrict__ cnt,        // MBLK counters, 64 uints apart (memset-0)
    float* __restrict__ partial)       // [T][NBLK][B][2] fp32 fc partials
{
  const int tid  = threadIdx.x;
  const int bid  = blockIdx.x;
  const int mb   = bid & 15;
  const int nb   = bid >> 4;
  const int lane = tid & 63;
  const int w    = tid >> 6;      // wave 0..3
  const int l15  = lane & 15;
  const int g4   = lane >> 4;     // 0..3

  extern __shared__ char smem[];
  __bf16* wlds   = (__bf16*)smem;                    // [4 g4][32 s][64 n][8]
  float4* win_s  = (float4*)(smem + OFF_WIN);
  float*  bias_s = (float*)(smem + OFF_BIAS);
  float*  wfc_s  = (float*)(smem + OFF_WFC);         // [64][2]
  __bf16 (*out_s)[72]     = (__bf16(*)[72])(smem + OFF_OUT);
  float  (*fc_s)[MWG][2]  = (float(*)[MWG][2])(smem + OFF_FCS);

  // ---- per-WG constants ----
  if (tid < NWG) {
    int n = nb * NWG + tid;
    bool ok = (n < HID);
    bias_s[tid] = ok ? (b_in[n] + b_hh[n]) : 0.f;
    win_s[tid]  = ok ? *reinterpret_cast<const float4*>(W_in + n * 4)
                     : make_float4(0.f, 0.f, 0.f, 0.f);
    wfc_s[tid * 2 + 0] = ok ? W_fc[n] : 0.f;
    wfc_s[tid * 2 + 1] = ok ? W_fc[HID + n] : 0.f;
  }

  // ---- W_hh slice -> LDS as MFMA B-fragments (once), fragment-major:
  //      frag(g4, s, n) at element ((g4*32 + s)*64 + n)*8 -> conflict-free b128 reads
  for (int i = 0; i < 32; ++i) {
    int idx = tid + i * 256;            // 8192 fragments total
    int n   = idx & 63;
    int s   = (idx >> 6) & 31;
    int gg  = idx >> 11;                // 0..3
    int n_glob = nb * NWG + n;
    int k0 = s * 32 + gg * 8;
    v8bf v;
    if (n_glob < HID && k0 < HID) {     // k0<1000 => k0<=992, 8 floats in-bounds
      const float4* p = reinterpret_cast<const float4*>(W_hh + (size_t)n_glob * HID + k0);
      float4 f0 = p[0], f1 = p[1];
      v[0] = (__bf16)f0.x; v[1] = (__bf16)f0.y; v[2] = (__bf16)f0.z; v[3] = (__bf16)f0.w;
      v[4] = (__bf16)f1.x; v[5] = (__bf16)f1.y; v[6] = (__bf16)f1.z; v[7] = (__bf16)f1.w;
    } else {
      #pragma unroll
      for (int j = 0; j < 8; ++j) v[j] = (__bf16)0.f;
    }
    *reinterpret_cast<v8bf*>(wlds + (size_t)((gg * 32 + s) * 64 + n) * 8) = v;
  }
  __syncthreads();

  const int n_loc  = (w << 4) + l15;       // [0,64): this thread's hidden col
  const int arow   = mb * MWG + l15;       // this lane's A row (batch index)
  const __bf16* bbase = wlds + (size_t)g4 * 16384 + (size_t)n_loc * 8;
  unsigned* mycnt = cnt + mb * 64;         // 256B-separated counter

  const float  bias = bias_s[n_loc];
  const float4 wi   = win_s[n_loc];
  const float  wf0  = wfc_s[n_loc * 2 + 0];
  const float  wf1  = wfc_s[n_loc * 2 + 1];

  for (int t = 0; t < TSTEPS; ++t) {
    const __bf16* hcur = h_buf + (size_t)(t & 1) * BATCH * HP;
    __bf16*       hnxt = h_buf + (size_t)((t & 1) ^ 1) * BATCH * HP;
    const __bf16* abase = hcur + (size_t)arow * HP + (g4 << 3);

    // A fragments: 32 x dwordx4, immediate offsets, all in flight
    v8bf a[32];
    #pragma unroll
    for (int s = 0; s < 32; ++s)
      a[s] = *reinterpret_cast<const v8bf*>(abase + s * 32);

    f32x4 acc4[4];
    #pragma unroll
    for (int c = 0; c < 4; ++c) acc4[c] = f32x4{0.f, 0.f, 0.f, 0.f};

    #pragma unroll
    for (int s = 0; s < 32; ++s) {
      v8bf b = *reinterpret_cast<const v8bf*>(bbase + s * 512);
      acc4[s & 3] = __builtin_amdgcn_mfma_f32_16x16x32_bf16(a[s], b, acc4[s & 3], 0, 0, 0);
    }

    f32x4 acc;
    #pragma unroll
    for (int j = 0; j < 4; ++j)
      acc[j] = (acc4[0][j] + acc4[1][j]) + (acc4[2][j] + acc4[3][j]);

    // ---- epilogue: xp + bias, tanh, stage h_new, fc partials ----
    float p0[4], p1[4];
    #pragma unroll
    for (int j = 0; j < 4; ++j) {
      const int m_loc  = (g4 << 2) + j;       // C row within tile
      const int b_glob = mb * MWG + m_loc;
      const float4 x = *reinterpret_cast<const float4*>(
          input + ((size_t)t * BATCH + b_glob) * IN_SZ);
      float pre = acc[j] + bias + x.x * wi.x + x.y * wi.y + x.z * wi.z + x.w * wi.w;
      float h = tanhf(pre);
      out_s[m_loc][n_loc] = (__bf16)h;
      p0[j] = h * wf0;
      p1[j] = h * wf1;
    }

    #pragma unroll
    for (int j = 0; j < 4; ++j) {
      float a0 = p0[j], a1 = p1[j];
      #pragma unroll
      for (int off = 8; off >= 1; off >>= 1) {
        a0 += __shfl_xor(a0, off, 64);
        a1 += __shfl_xor(a1, off, 64);
      }
      if (l15 == 0) {
        fc_s[w][(g4 << 2) + j][0] = a0;
        fc_s[w][(g4 << 2) + j][1] = a1;
      }
    }

    __syncthreads();

    if (tid < 32) {   // combine 4 waves' fc partials -> global
      int m = tid >> 1, o = tid & 1;
      float s = (fc_s[0][m][o] + fc_s[1][m][o]) + (fc_s[2][m][o] + fc_s[3][m][o]);
      partial[(((size_t)t * NBLK + nb) * BATCH + (mb * MWG + m)) * 2 + o] = s;
    }
    if (tid < 128) {  // coalesced 16B stores of h_new tile
      int r = tid >> 3, c = (tid & 7) << 3;
      v8bf v = *reinterpret_cast<const v8bf*>(&out_s[r][c]);
      *reinterpret_cast<v8bf*>(hnxt + (size_t)(mb * MWG + r) * HP + nb * NWG + c) = v;
    }

    // ---- 16-WG phase barrier for this batch-group ----
    if (t < TSTEPS - 1) {
      __syncthreads();   // drains vmcnt: all waves' h stores are in L2
      if (tid == 0) {
        __builtin_amdgcn_fence(__ATOMIC_RELEASE, "agent");   // writeback L2
        __hip_atomic_fetch_add(mycnt, 1u, __ATOMIC_RELEASE, __HIP_MEMORY_SCOPE_AGENT);
        const unsigned tgt = (unsigned)(NBLK * (t + 1));
        while (__hip_atomic_load(mycnt, __ATOMIC_RELAXED, __HIP_MEMORY_SCOPE_AGENT) < tgt) {}
        __builtin_amdgcn_fence(__ATOMIC_ACQUIRE, "agent");   // invalidate L1/L2
      }
      __syncthreads();
    }
  }
}

__global__ void fc_finish(const float* __restrict__ partial,
                          const float* __restrict__ b_fc,
                          float* __restrict__ out)
{
  const int t = blockIdx.x;       // 200 blocks
  const int tid = threadIdx.x;    // 512 = 256 b x 2 o
  const int o = tid & 1;
  float s = b_fc[o];
  #pragma unroll
  for (int p = 0; p < NBLK; ++p)
    s += partial[((size_t)t * NBLK + p) * (BATCH * 2) + tid];
  out[(size_t)t * 512 + tid] = tanhf(s);
}

extern "C" void kernel_launch(void* const* d_in, const int* in_sizes, int n_in,
                              void* d_out, int out_size, void* d_ws, size_t ws_size,
                              hipStream_t stream) {
  const float* input = (const float*)d_in[0];
  // d_in[1] = target (unused by forward output)
  const float* W_in  = (const float*)d_in[2];
  const float* b_in  = (const float*)d_in[3];
  const float* W_hh  = (const float*)d_in[4];
  const float* b_hh  = (const float*)d_in[5];
  const float* W_fc  = (const float*)d_in[6];
  const float* b_fc  = (const float*)d_in[7];
  float* out = (float*)d_out;

  __bf16*   h_buf   = (__bf16*)d_ws;
  unsigned* cnt     = (unsigned*)((char*)d_ws + H_BYTES);
  float*    partial = (float*)((char*)d_ws + PARTIAL_OFF);

  // zero h0 (both buffers) + barrier counters; capture-legal stream op
  hipMemsetAsync(d_ws, 0, H_BYTES + CNT_BYTES, stream);

  // host-side, idempotent, capture-safe: allow 132KB dynamic LDS
  hipFuncSetAttribute((const void*)elman_rnn,
                      hipFuncAttributeMaxDynamicSharedMemorySize, SMEM_BYTES);

  void* args[] = { (void*)&input, (void*)&W_in, (void*)&b_in, (void*)&W_hh,
                   (void*)&b_hh, (void*)&W_fc, (void*)&h_buf, (void*)&cnt,
                   (void*)&partial };
  hipLaunchCooperativeKernel((const void*)elman_rnn, dim3(256), dim3(256),
                             args, SMEM_BYTES, stream);

  fc_finish<<<TSTEPS, 512, 0, stream>>>(partial, b_fc, out);
}